// Round 1
// baseline (330.788 us; speedup 1.0000x reference)
//
#include <hip/hip_runtime.h>

// SpatialTransformer: bilinear warp of src[B,H,W,1] by flow[B,H,W,2].
// B=32, H=768, W=768. Pure fp32, memory-bound gather.

#define BB 32
#define HH 768
#define WW 768
#define HWN (HH * WW)

__global__ __launch_bounds__(256) void st_warp_kernel(
    const float* __restrict__ src,
    const float* __restrict__ flow,
    float* __restrict__ out,
    int n)
{
    int p = blockIdx.x * blockDim.x + threadIdx.x;
    if (p >= n) return;

    // decode (b, y, x) from flat pixel index
    int b   = p / HWN;
    int rem = p - b * HWN;
    int y   = rem / WW;
    int x   = rem - y * WW;

    // coalesced flow read: (dx, dy) per pixel
    float2 f = reinterpret_cast<const float2*>(flow)[p];
    float gx = (float)x + f.x;
    float gy = (float)y + f.y;

    float x0f = floorf(gx);
    float y0f = floorf(gy);
    float x1f = x0f + 1.0f;
    float y1f = y0f + 1.0f;

    // weights from UNCLIPPED corners (reference semantics)
    float wxe = gx - x0f;            // east weight in x
    float wxw = x1f - gx;            // west
    float wys = gy - y0f;            // south weight in y
    float wyn = y1f - gy;            // north
    float wa = wxw * wyn;
    float wb = wxe * wyn;
    float wc = wxw * wys;
    float wd = wxe * wys;

    // clamped integer corner indices
    int x0 = (int)fminf(fmaxf(x0f, 0.0f), (float)(WW - 1));
    int x1 = (int)fminf(fmaxf(x1f, 0.0f), (float)(WW - 1));
    int y0 = (int)fminf(fmaxf(y0f, 0.0f), (float)(HH - 1));
    int y1 = (int)fminf(fmaxf(y1f, 0.0f), (float)(HH - 1));

    const float* img = src + b * HWN;
    int r0 = y0 * WW;
    int r1 = y1 * WW;
    float va = img[r0 + x0];
    float vb = img[r0 + x1];
    float vc = img[r1 + x0];
    float vd = img[r1 + x1];

    out[p] = wa * va + wb * vb + wc * vc + wd * vd;
}

extern "C" void kernel_launch(void* const* d_in, const int* in_sizes, int n_in,
                              void* d_out, int out_size, void* d_ws, size_t ws_size,
                              hipStream_t stream) {
    const float* src  = (const float*)d_in[0];
    const float* flow = (const float*)d_in[1];
    float* out = (float*)d_out;

    int n = BB * HWN;  // = out_size
    int block = 256;
    int grid = (n + block - 1) / block;
    st_warp_kernel<<<grid, block, 0, stream>>>(src, flow, out, n);
}

// Round 5
// 304.881 us; speedup vs baseline: 1.0850x; 1.0850x over previous
//
#include <hip/hip_runtime.h>

// SpatialTransformer bilinear warp, B=32 H=768 W=768 fp32.
// 2D-tiled gather: block = 64x16 output tile (16 thr x * 16 thr y, 4 px/thread).
// Nontemporal flow/out keep caches dedicated to src gathers.

#define BB 32
#define HH 768
#define WW 768
#define HWN (HH * WW)

typedef float fvec4 __attribute__((ext_vector_type(4)));

__global__ __launch_bounds__(256) void st_warp_kernel(
    const float* __restrict__ src,
    const float* __restrict__ flow,
    float* __restrict__ out)
{
    int tx = threadIdx.x & 15;           // 16 threads across x
    int ty = threadIdx.x >> 4;           // 16 rows
    int xb = blockIdx.x * 64 + tx * 4;   // first of 4 consecutive x pixels
    int y  = blockIdx.y * 16 + ty;
    int b  = blockIdx.z;

    int p = (b * HH + y) * WW + xb;      // flat pixel index of pixel 0

    // streamed, read-once: nontemporal float4 loads (32B aligned: p % 4 == 0)
    const fvec4* fp = reinterpret_cast<const fvec4*>(flow + 2 * p);
    fvec4 f01 = __builtin_nontemporal_load(fp);
    fvec4 f23 = __builtin_nontemporal_load(fp + 1);

    const float* img = src + b * HWN;

    float fx[4] = {f01.x, f01.z, f23.x, f23.z};
    float fy[4] = {f01.y, f01.w, f23.y, f23.w};
    float res[4];

    #pragma unroll
    for (int i = 0; i < 4; ++i) {
        float gx = (float)(xb + i) + fx[i];
        float gy = (float)y + fy[i];

        float x0f = floorf(gx);
        float y0f = floorf(gy);
        float x1f = x0f + 1.0f;
        float y1f = y0f + 1.0f;

        // weights from UNCLIPPED corners (reference semantics)
        float wa = (x1f - gx) * (y1f - gy);
        float wb = (gx - x0f) * (y1f - gy);
        float wc = (x1f - gx) * (gy - y0f);
        float wd = (gx - x0f) * (gy - y0f);

        int x0 = (int)fminf(fmaxf(x0f, 0.0f), (float)(WW - 1));
        int x1 = (int)fminf(fmaxf(x1f, 0.0f), (float)(WW - 1));
        int y0 = (int)fminf(fmaxf(y0f, 0.0f), (float)(HH - 1));
        int y1 = (int)fminf(fmaxf(y1f, 0.0f), (float)(HH - 1));

        int r0 = y0 * WW;
        int r1 = y1 * WW;
        float va = img[r0 + x0];
        float vb = img[r0 + x1];
        float vc = img[r1 + x0];
        float vd = img[r1 + x1];

        res[i] = wa * va + wb * vb + wc * vc + wd * vd;
    }

    fvec4 o = {res[0], res[1], res[2], res[3]};
    __builtin_nontemporal_store(o, reinterpret_cast<fvec4*>(out + p));
}

extern "C" void kernel_launch(void* const* d_in, const int* in_sizes, int n_in,
                              void* d_out, int out_size, void* d_ws, size_t ws_size,
                              hipStream_t stream) {
    const float* src  = (const float*)d_in[0];
    const float* flow = (const float*)d_in[1];
    float* out = (float*)d_out;

    dim3 grid(WW / 64, HH / 16, BB);   // 12 x 48 x 32
    st_warp_kernel<<<grid, 256, 0, stream>>>(src, flow, out);
}

// Round 7
// 284.099 us; speedup vs baseline: 1.1643x; 1.0731x over previous
//
#include <hip/hip_runtime.h>

// SpatialTransformer bilinear warp, B=32 H=768 W=768 fp32.
// 2D-tiled gather: block = 64x16 tile, 4 px/thread.
// Paired-corner loads: (va,vb) and (vc,vd) each fetched as one 8B
// global_load_dwordx2 at pl=min(x0,W-2), clamp resolved via cndmask.
// Nontemporal flow/out keep caches dedicated to src gathers.

#define BB 32
#define HH 768
#define WW 768
#define HWN (HH * WW)

typedef float fvec4 __attribute__((ext_vector_type(4)));
typedef float fvec2a4 __attribute__((ext_vector_type(2), aligned(4)));

__global__ __launch_bounds__(256) void st_warp_kernel(
    const float* __restrict__ src,
    const float* __restrict__ flow,
    float* __restrict__ out)
{
    int tx = threadIdx.x & 15;           // 16 threads across x
    int ty = threadIdx.x >> 4;           // 16 rows
    int xb = blockIdx.x * 64 + tx * 4;   // first of 4 consecutive x pixels
    int y  = blockIdx.y * 16 + ty;
    int b  = blockIdx.z;

    int p = (b * HH + y) * WW + xb;      // flat pixel index of pixel 0

    const fvec4* fp = reinterpret_cast<const fvec4*>(flow + 2 * p);
    fvec4 f01 = __builtin_nontemporal_load(fp);
    fvec4 f23 = __builtin_nontemporal_load(fp + 1);

    const float* img = src + b * HWN;

    float fx[4] = {f01.x, f01.z, f23.x, f23.z};
    float fy[4] = {f01.y, f01.w, f23.y, f23.w};
    float res[4];

    #pragma unroll
    for (int i = 0; i < 4; ++i) {
        float gx = (float)(xb + i) + fx[i];
        float gy = (float)y + fy[i];

        float x0f = floorf(gx);
        float y0f = floorf(gy);
        float x1f = x0f + 1.0f;
        float y1f = y0f + 1.0f;

        // weights from UNCLIPPED corners (reference semantics)
        float wa = (x1f - gx) * (y1f - gy);
        float wb = (gx - x0f) * (y1f - gy);
        float wc = (x1f - gx) * (gy - y0f);
        float wd = (gx - x0f) * (gy - y0f);

        int x0 = (int)fminf(fmaxf(x0f, 0.0f), (float)(WW - 1));
        int x1 = (int)fminf(fmaxf(x1f, 0.0f), (float)(WW - 1));
        int y0 = (int)fminf(fmaxf(y0f, 0.0f), (float)(HH - 1));
        int y1 = (int)fminf(fmaxf(y1f, 0.0f), (float)(HH - 1));

        int pl = min(x0, WW - 2);        // pair base; pl and pl+1 always in-row
        int r0 = y0 * WW;
        int r1 = y1 * WW;

        fvec2a4 t = *reinterpret_cast<const fvec2a4*>(img + r0 + pl);
        fvec2a4 u = *reinterpret_cast<const fvec2a4*>(img + r1 + pl);

        // normal: x0==pl -> (lo,hi); left clamp x0==x1==0 -> (lo,lo);
        // right clamp x0==x1==767, pl=766 -> (hi,hi)
        float va = (x0 == pl) ? t.x : t.y;
        float vb = (x1 == pl) ? t.x : t.y;
        float vc = (x0 == pl) ? u.x : u.y;
        float vd = (x1 == pl) ? u.x : u.y;

        res[i] = wa * va + wb * vb + wc * vc + wd * vd;
    }

    fvec4 o = {res[0], res[1], res[2], res[3]};
    __builtin_nontemporal_store(o, reinterpret_cast<fvec4*>(out + p));
}

extern "C" void kernel_launch(void* const* d_in, const int* in_sizes, int n_in,
                              void* d_out, int out_size, void* d_ws, size_t ws_size,
                              hipStream_t stream) {
    const float* src  = (const float*)d_in[0];
    const float* flow = (const float*)d_in[1];
    float* out = (float*)d_out;

    dim3 grid(WW / 64, HH / 16, BB);   // 12 x 48 x 32
    st_warp_kernel<<<grid, 256, 0, stream>>>(src, flow, out);
}